// Round 4
// baseline (130.806 us; speedup 1.0000x reference)
//
#include <hip/hip_runtime.h>

#define NN 8192
#define DIN 7
#define DH 8
#define DOUT 23
#define CUTOFF 3.6f
#define SLOPE 0.01f
#define CHUNK 64             // j-chunk per k3 block
#define NCHUNK (NN / CHUNK)  // 128
#define RPT 4                // rows per thread in k3

__device__ __forceinline__ float leaky(float v) { return v >= 0.0f ? v : SLOPE * v; }

// Per-node feature pipeline. MUST be the single shared implementation so k3's
// staged E/ev and k4's recomputed E/ev are bit-identical (exact diagonal cancel).
__device__ __forceinline__ void node_feats(
    const float* __restrict__ x,
    const float* __restrict__ W1, const float* __restrict__ b1,
    const float* __restrict__ W2, const float* __restrict__ b2,
    const float* __restrict__ W3, const float* __restrict__ b3,
    int n, float coord[3], float& E, float ev[7])
{
    float xi[DIN];
#pragma unroll
    for (int d = 0; d < DIN; ++d) xi[d] = x[n * DIN + d];
    coord[0] = xi[0]; coord[1] = xi[1]; coord[2] = xi[2];

    float h1[DH];
#pragma unroll
    for (int k = 0; k < DH; ++k) {
        float t = b1[k];
#pragma unroll
        for (int d = 0; d < DIN; ++d) t = fmaf(W1[k * DIN + d], xi[d], t);
        h1[k] = leaky(t);
    }
    float h2[DH];
#pragma unroll
    for (int k = 0; k < DH; ++k) {
        float t = b2[k];
#pragma unroll
        for (int d = 0; d < DH; ++d) t = fmaf(W2[k * DH + d], h1[d], t);
        h2[k] = leaky(t);
    }
    float h3[DOUT];
#pragma unroll
    for (int m = 0; m < DOUT; ++m) {
        float t = b3[m];
#pragma unroll
        for (int d = 0; d < DH; ++d) t = fmaf(W3[m * DH + d], h2[d], t);
        h3[m] = t;
    }
    float s = 0.0f;
#pragma unroll
    for (int k = 0; k < 8; ++k) s = fmaf(h3[7 + k], h3[15 + k], s);
    // |s| is O(1) (weights scaled 0.1) -> exp without max-shift is safe in fp32;
    // the softmax ratio is shift-invariant so this matches the reference.
    E = expf(s);
#pragma unroll
    for (int q = 0; q < 7; ++q) ev[q] = h3[q] * E;
}

// ---------------- K3: O(N^2) masked accumulation, fused staging, R=4 rows/thread --------
// grid (8, 128): blockIdx.x -> 1024 rows (4/thread), blockIdx.y -> 64-wide j chunk.
// 1024 blocks = 4 blocks/CU = 4 waves/SIMD (latency hiding; R3's 2/SIMD stalled at 47%).
__global__ __launch_bounds__(256, 4) void k3_fused(
    const float* __restrict__ x,
    const float* __restrict__ W1, const float* __restrict__ b1,
    const float* __restrict__ W2, const float* __restrict__ b2,
    const float* __restrict__ W3, const float* __restrict__ b3,
    float* __restrict__ accum)
{
    __shared__ float4 sA[CHUNK];   // cx, cy, cz, E
    __shared__ float4 sB[CHUNK];   // E*vals[0..3]
    __shared__ float4 sC[CHUNK];   // E*vals[4..6], 0

    int tid = threadIdx.x;

    // stage chunk: recompute node features for this block's 64 j's (one wave)
    if (tid < CHUNK) {
        int j = blockIdx.y * CHUNK + tid;
        float cj[3], E, ev[7];
        node_feats(x, W1, b1, W2, b2, W3, b3, j, cj, E, ev);
        sA[tid] = make_float4(cj[0], cj[1], cj[2], E);
        sB[tid] = make_float4(ev[0], ev[1], ev[2], ev[3]);
        sC[tid] = make_float4(ev[4], ev[5], ev[6], 0.0f);
    }

    // row coords for the 4 rows this thread owns
    int r0 = blockIdx.x * (256 * RPT) + tid;
    float cx[RPT], cy[RPT], cz[RPT];
#pragma unroll
    for (int k = 0; k < RPT; ++k) {
        int r = r0 + 256 * k;
        cx[k] = x[r * DIN + 0];
        cy[k] = x[r * DIN + 1];
        cz[k] = x[r * DIN + 2];
    }

    float acc[RPT][8];
#pragma unroll
    for (int k = 0; k < RPT; ++k)
#pragma unroll
        for (int q = 0; q < 8; ++q) acc[k][q] = 0.0f;

    __syncthreads();

#pragma unroll 4
    for (int jj = 0; jj < CHUNK; ++jj) {
        float4 cj = sA[jj];
        float4 q0 = sB[jj];
        float4 q1 = sC[jj];
#pragma unroll
        for (int k = 0; k < RPT; ++k) {
            // exact ref order: (|dx| + |dy|) + |dz|
            float t = fabsf(cx[k] - cj.x) + fabsf(cy[k] - cj.y) + fabsf(cz[k] - cj.z);
            float w = (t <= CUTOFF) ? 1.0f : 0.0f;
            acc[k][0] = fmaf(w, cj.w, acc[k][0]);
            acc[k][1] = fmaf(w, q0.x, acc[k][1]);
            acc[k][2] = fmaf(w, q0.y, acc[k][2]);
            acc[k][3] = fmaf(w, q0.z, acc[k][3]);
            acc[k][4] = fmaf(w, q0.w, acc[k][4]);
            acc[k][5] = fmaf(w, q1.x, acc[k][5]);
            acc[k][6] = fmaf(w, q1.y, acc[k][6]);
            acc[k][7] = fmaf(w, q1.z, acc[k][7]);
        }
    }

    // transposed accum [q][row]: consecutive tid -> consecutive addresses per instr
#pragma unroll
    for (int k = 0; k < RPT; ++k) {
        int r = r0 + 256 * k;
#pragma unroll
        for (int q = 0; q < 8; ++q) atomicAdd(&accum[q * NN + r], acc[k][q]);
    }
}

// ---------------- K4: recompute row features, finalize, encoder/decoder, write out -------
__global__ __launch_bounds__(256) void k4_final(
    const float* __restrict__ x,
    const float* __restrict__ W1, const float* __restrict__ b1,
    const float* __restrict__ W2, const float* __restrict__ b2,
    const float* __restrict__ W3, const float* __restrict__ b3,
    const float* __restrict__ We, const float* __restrict__ be,
    const float* __restrict__ Wd, const float* __restrict__ bd,
    const float* __restrict__ accum, float* __restrict__ out)
{
    int n = blockIdx.x * 256 + threadIdx.x;

    float cn[3], E, ev[7];
    node_feats(x, W1, b1, W2, b2, W3, b3, n, cn, E, ev);

    // remove diagonal (dist=0 always passes cutoff); bit-identical recompute -> exact
    float denom = accum[0 * NN + n] - E;
    denom = fmaxf(denom, 1e-30f);
    float inv = 1.0f / denom;

    float inp[14];
#pragma unroll
    for (int d = 0; d < DIN; ++d) inp[d] = x[n * DIN + d];
#pragma unroll
    for (int q = 0; q < 7; ++q) inp[7 + q] = (accum[(q + 1) * NN + n] - ev[q]) * inv;

    float codes[DH];
#pragma unroll
    for (int k = 0; k < DH; ++k) {
        float t = be[k];
#pragma unroll
        for (int d = 0; d < 14; ++d) t = fmaf(We[k * 14 + d], inp[d], t);
        codes[k] = leaky(t);
    }
#pragma unroll
    for (int cc = 0; cc < DIN; ++cc) {
        float t = bd[cc];
#pragma unroll
        for (int k = 0; k < DH; ++k) t = fmaf(Wd[cc * DH + k], codes[k], t);
        out[(size_t)n * DIN + cc] = t;
    }
}

extern "C" void kernel_launch(void* const* d_in, const int* in_sizes, int n_in,
                              void* d_out, int out_size, void* d_ws, size_t ws_size,
                              hipStream_t stream) {
    const float* x  = (const float*)d_in[0];
    const float* W1 = (const float*)d_in[1];
    const float* b1 = (const float*)d_in[2];
    const float* W2 = (const float*)d_in[3];
    const float* b2 = (const float*)d_in[4];
    const float* W3 = (const float*)d_in[5];
    const float* b3 = (const float*)d_in[6];
    const float* We = (const float*)d_in[7];
    const float* be = (const float*)d_in[8];
    const float* Wd = (const float*)d_in[9];
    const float* bd = (const float*)d_in[10];
    float* out = (float*)d_out;

    float* accum = (float*)d_ws;  // 8 * 8192 * 4 = 262144 B

    hipMemsetAsync(accum, 0, 8 * NN * sizeof(float), stream);
    dim3 g3(NN / (256 * RPT), NCHUNK);  // (8, 128)
    k3_fused<<<g3, 256, 0, stream>>>(x, W1, b1, W2, b2, W3, b3, accum);
    k4_final<<<32, 256, 0, stream>>>(x, W1, b1, W2, b2, W3, b3, We, be, Wd, bd, accum, out);
}

// Round 5
// 121.842 us; speedup vs baseline: 1.0736x; 1.0736x over previous
//
#include <hip/hip_runtime.h>

#define NN 8192
#define DIN 7
#define DH 8
#define DOUT 23
#define CUTOFF 3.6f
#define SLOPE 0.01f
#define CHUNK 128            // j-chunk per k3 block
#define NCHUNK (NN / CHUNK)  // 64
#define RPT 4                // rows per thread in k3

__device__ __forceinline__ float leaky(float v) { return v >= 0.0f ? v : SLOPE * v; }

// Per-node feature pipeline. MUST be the single shared implementation so k3's
// staged E/ev and k4's recomputed E/ev are bit-identical (exact diagonal cancel).
__device__ __forceinline__ void node_feats(
    const float* __restrict__ x,
    const float* __restrict__ W1, const float* __restrict__ b1,
    const float* __restrict__ W2, const float* __restrict__ b2,
    const float* __restrict__ W3, const float* __restrict__ b3,
    int n, float coord[3], float& E, float ev[7])
{
    float xi[DIN];
#pragma unroll
    for (int d = 0; d < DIN; ++d) xi[d] = x[n * DIN + d];
    coord[0] = xi[0]; coord[1] = xi[1]; coord[2] = xi[2];

    float h1[DH];
#pragma unroll
    for (int k = 0; k < DH; ++k) {
        float t = b1[k];
#pragma unroll
        for (int d = 0; d < DIN; ++d) t = fmaf(W1[k * DIN + d], xi[d], t);
        h1[k] = leaky(t);
    }
    float h2[DH];
#pragma unroll
    for (int k = 0; k < DH; ++k) {
        float t = b2[k];
#pragma unroll
        for (int d = 0; d < DH; ++d) t = fmaf(W2[k * DH + d], h1[d], t);
        h2[k] = leaky(t);
    }
    float h3[DOUT];
#pragma unroll
    for (int m = 0; m < DOUT; ++m) {
        float t = b3[m];
#pragma unroll
        for (int d = 0; d < DH; ++d) t = fmaf(W3[m * DH + d], h2[d], t);
        h3[m] = t;
    }
    float s = 0.0f;
#pragma unroll
    for (int k = 0; k < 8; ++k) s = fmaf(h3[7 + k], h3[15 + k], s);
    // |s| is O(1) (weights scaled 0.1) -> exp without max-shift is safe in fp32;
    // the softmax ratio is shift-invariant so this matches the reference.
    E = expf(s);
#pragma unroll
    for (int q = 0; q < 7; ++q) ev[q] = h3[q] * E;
}

// ---------------- K3: O(N^2) masked accumulation, fused staging, R=4 rows/thread --------
// grid (8, 64): blockIdx.x -> 1024 rows (4/thread), blockIdx.y -> 128-wide j chunk.
// NO atomics: each y-block writes a private partial slice part[y][q][row].
__global__ __launch_bounds__(256, 2) void k3_fused(
    const float* __restrict__ x,
    const float* __restrict__ W1, const float* __restrict__ b1,
    const float* __restrict__ W2, const float* __restrict__ b2,
    const float* __restrict__ W3, const float* __restrict__ b3,
    float* __restrict__ part)
{
    __shared__ float4 sA[CHUNK];   // cx, cy, cz, E
    __shared__ float4 sB[CHUNK];   // E*vals[0..3]
    __shared__ float4 sC[CHUNK];   // E*vals[4..6], 0

    int tid = threadIdx.x;

    // stage chunk: recompute node features for this block's 128 j's (2 waves)
    if (tid < CHUNK) {
        int j = blockIdx.y * CHUNK + tid;
        float cj[3], E, ev[7];
        node_feats(x, W1, b1, W2, b2, W3, b3, j, cj, E, ev);
        sA[tid] = make_float4(cj[0], cj[1], cj[2], E);
        sB[tid] = make_float4(ev[0], ev[1], ev[2], ev[3]);
        sC[tid] = make_float4(ev[4], ev[5], ev[6], 0.0f);
    }

    // row coords for the 4 rows this thread owns
    int r0 = blockIdx.x * (256 * RPT) + tid;
    float cx[RPT], cy[RPT], cz[RPT];
#pragma unroll
    for (int k = 0; k < RPT; ++k) {
        int r = r0 + 256 * k;
        cx[k] = x[r * DIN + 0];
        cy[k] = x[r * DIN + 1];
        cz[k] = x[r * DIN + 2];
    }

    float acc[RPT][8];
#pragma unroll
    for (int k = 0; k < RPT; ++k)
#pragma unroll
        for (int q = 0; q < 8; ++q) acc[k][q] = 0.0f;

    __syncthreads();

#pragma unroll 4
    for (int jj = 0; jj < CHUNK; ++jj) {
        float4 cj = sA[jj];
        float4 q0 = sB[jj];
        float4 q1 = sC[jj];
#pragma unroll
        for (int k = 0; k < RPT; ++k) {
            // exact ref order: (|dx| + |dy|) + |dz|
            float t = fabsf(cx[k] - cj.x) + fabsf(cy[k] - cj.y) + fabsf(cz[k] - cj.z);
            float w = (t <= CUTOFF) ? 1.0f : 0.0f;
            acc[k][0] = fmaf(w, cj.w, acc[k][0]);
            acc[k][1] = fmaf(w, q0.x, acc[k][1]);
            acc[k][2] = fmaf(w, q0.y, acc[k][2]);
            acc[k][3] = fmaf(w, q0.z, acc[k][3]);
            acc[k][4] = fmaf(w, q0.w, acc[k][4]);
            acc[k][5] = fmaf(w, q1.x, acc[k][5]);
            acc[k][6] = fmaf(w, q1.y, acc[k][6]);
            acc[k][7] = fmaf(w, q1.z, acc[k][7]);
        }
    }

    // plain coalesced stores into this chunk's private slice: part[y][q][row]
    float* base = part + (size_t)blockIdx.y * 8 * NN;
#pragma unroll
    for (int k = 0; k < RPT; ++k) {
        int r = r0 + 256 * k;
#pragma unroll
        for (int q = 0; q < 8; ++q) base[q * NN + r] = acc[k][q];
    }
}

// ---------------- K_red: sum the NCHUNK partial slices -> accum[q][row] -----------------
// one thread per (q, row): 65536 threads = 256 blocks.
__global__ __launch_bounds__(256) void k_red(
    const float* __restrict__ part, float* __restrict__ accum)
{
    int t = blockIdx.x * 256 + threadIdx.x;   // 0..65535
    int q = t >> 13;                          // 0..7
    int r = t & (NN - 1);
    const float* p = part + (size_t)q * NN + r;
    float s = 0.0f;
#pragma unroll 8
    for (int y = 0; y < NCHUNK; ++y) s += p[(size_t)y * 8 * NN];
    accum[(size_t)q * NN + r] = s;
}

// ---------------- K4: recompute row features, finalize, encoder/decoder, write out -------
__global__ __launch_bounds__(256) void k4_final(
    const float* __restrict__ x,
    const float* __restrict__ W1, const float* __restrict__ b1,
    const float* __restrict__ W2, const float* __restrict__ b2,
    const float* __restrict__ W3, const float* __restrict__ b3,
    const float* __restrict__ We, const float* __restrict__ be,
    const float* __restrict__ Wd, const float* __restrict__ bd,
    const float* __restrict__ accum, float* __restrict__ out)
{
    int n = blockIdx.x * 256 + threadIdx.x;

    float cn[3], E, ev[7];
    node_feats(x, W1, b1, W2, b2, W3, b3, n, cn, E, ev);

    // remove diagonal (dist=0 always passes cutoff); bit-identical recompute -> exact
    float denom = accum[0 * NN + n] - E;
    denom = fmaxf(denom, 1e-30f);
    float inv = 1.0f / denom;

    float inp[14];
#pragma unroll
    for (int d = 0; d < DIN; ++d) inp[d] = x[n * DIN + d];
#pragma unroll
    for (int q = 0; q < 7; ++q) inp[7 + q] = (accum[(q + 1) * NN + n] - ev[q]) * inv;

    float codes[DH];
#pragma unroll
    for (int k = 0; k < DH; ++k) {
        float t = be[k];
#pragma unroll
        for (int d = 0; d < 14; ++d) t = fmaf(We[k * 14 + d], inp[d], t);
        codes[k] = leaky(t);
    }
#pragma unroll
    for (int cc = 0; cc < DIN; ++cc) {
        float t = bd[cc];
#pragma unroll
        for (int k = 0; k < DH; ++k) t = fmaf(Wd[cc * DH + k], codes[k], t);
        out[(size_t)n * DIN + cc] = t;
    }
}

extern "C" void kernel_launch(void* const* d_in, const int* in_sizes, int n_in,
                              void* d_out, int out_size, void* d_ws, size_t ws_size,
                              hipStream_t stream) {
    const float* x  = (const float*)d_in[0];
    const float* W1 = (const float*)d_in[1];
    const float* b1 = (const float*)d_in[2];
    const float* W2 = (const float*)d_in[3];
    const float* b2 = (const float*)d_in[4];
    const float* W3 = (const float*)d_in[5];
    const float* b3 = (const float*)d_in[6];
    const float* We = (const float*)d_in[7];
    const float* be = (const float*)d_in[8];
    const float* Wd = (const float*)d_in[9];
    const float* bd = (const float*)d_in[10];
    float* out = (float*)d_out;

    char* ws = (char*)d_ws;
    float* part  = (float*)ws;                                  // 64*8*8192*4 = 16 MiB
    float* accum = (float*)(ws + (size_t)NCHUNK * 8 * NN * 4);  // 8*8192*4 = 256 KiB

    dim3 g3(NN / (256 * RPT), NCHUNK);  // (8, 64)
    k3_fused<<<g3, 256, 0, stream>>>(x, W1, b1, W2, b2, W3, b3, part);
    k_red<<<256, 256, 0, stream>>>(part, accum);
    k4_final<<<32, 256, 0, stream>>>(x, W1, b1, W2, b2, W3, b3, We, be, Wd, bd, accum, out);
}

// Round 6
// 121.827 us; speedup vs baseline: 1.0737x; 1.0001x over previous
//
#include <hip/hip_runtime.h>

#define NN 8192
#define DIN 7
#define DH 8
#define DOUT 23
#define CUTOFF 3.6f
#define SLOPE 0.01f
#define CHUNK 128            // j-chunk per k3 block
#define NCHUNK (NN / CHUNK)  // 64
#define RPT 8                // rows per thread in k3
#define RSTRIDE 65           // padded lane stride (words) for the reduce buffer

__device__ __forceinline__ float leaky(float v) { return v >= 0.0f ? v : SLOPE * v; }

// Per-node feature pipeline. MUST be the single shared implementation so k3's
// staged E/ev and k4's recomputed E/ev are bit-identical (exact diagonal cancel).
__device__ __forceinline__ void node_feats(
    const float* __restrict__ x,
    const float* __restrict__ W1, const float* __restrict__ b1,
    const float* __restrict__ W2, const float* __restrict__ b2,
    const float* __restrict__ W3, const float* __restrict__ b3,
    int n, float coord[3], float& E, float ev[7])
{
    float xi[DIN];
#pragma unroll
    for (int d = 0; d < DIN; ++d) xi[d] = x[n * DIN + d];
    coord[0] = xi[0]; coord[1] = xi[1]; coord[2] = xi[2];

    float h1[DH];
#pragma unroll
    for (int k = 0; k < DH; ++k) {
        float t = b1[k];
#pragma unroll
        for (int d = 0; d < DIN; ++d) t = fmaf(W1[k * DIN + d], xi[d], t);
        h1[k] = leaky(t);
    }
    float h2[DH];
#pragma unroll
    for (int k = 0; k < DH; ++k) {
        float t = b2[k];
#pragma unroll
        for (int d = 0; d < DH; ++d) t = fmaf(W2[k * DH + d], h1[d], t);
        h2[k] = leaky(t);
    }
    float h3[DOUT];
#pragma unroll
    for (int m = 0; m < DOUT; ++m) {
        float t = b3[m];
#pragma unroll
        for (int d = 0; d < DH; ++d) t = fmaf(W3[m * DH + d], h2[d], t);
        h3[m] = t;
    }
    float s = 0.0f;
#pragma unroll
    for (int k = 0; k < 8; ++k) s = fmaf(h3[7 + k], h3[15 + k], s);
    // |s| is O(1) (weights scaled 0.1) -> exp without max-shift is safe in fp32;
    // the softmax ratio is shift-invariant so this matches the reference.
    E = expf(s);
#pragma unroll
    for (int q = 0; q < 7; ++q) ev[q] = h3[q] * E;
}

// ---------------- K3: O(N^2) masked accumulation, RPT=8 rows/thread, j-split waves ------
// grid (8, 64): 512 blocks (2/CU). Block = 256 threads = (128 row-lanes) x (2 j-halves).
// Each thread: 8 rows x 64 jj. Each broadcast LDS read now feeds 8 rows (2x R3's reuse)
// -> LDS pipe 37k -> 18.4k cyc/CU; VALU (12.8 us) becomes the binding pipe.
__global__ __launch_bounds__(256, 2) void k3_fused(
    const float* __restrict__ x,
    const float* __restrict__ W1, const float* __restrict__ b1,
    const float* __restrict__ W2, const float* __restrict__ b2,
    const float* __restrict__ W3, const float* __restrict__ b3,
    float* __restrict__ accum)
{
    __shared__ float4 sA[CHUNK];        // cx, cy, cz, E
    __shared__ float4 sB[CHUNK];        // E*vals[0..3]
    __shared__ float4 sC[CHUNK];        // E*vals[4..6], 0
    __shared__ float sRed[128 * RSTRIDE];  // 33.3 KB cross-half reduce buffer

    int tid = threadIdx.x;
    int lane = tid & 127;    // row-group id (two waves share a row set)
    int jhalf = tid >> 7;    // 0: jj[0,64)  1: jj[64,128)

    // stage chunk: recompute node features for this block's 128 j's
    if (tid < CHUNK) {
        int j = blockIdx.y * CHUNK + tid;
        float cj[3], E, ev[7];
        node_feats(x, W1, b1, W2, b2, W3, b3, j, cj, E, ev);
        sA[tid] = make_float4(cj[0], cj[1], cj[2], E);
        sB[tid] = make_float4(ev[0], ev[1], ev[2], ev[3]);
        sC[tid] = make_float4(ev[4], ev[5], ev[6], 0.0f);
    }

    // row coords for the 8 rows this thread owns (rows stride 128)
    int r0 = blockIdx.x * 1024 + lane;
    float cx[RPT], cy[RPT], cz[RPT];
#pragma unroll
    for (int k = 0; k < RPT; ++k) {
        int r = r0 + 128 * k;
        cx[k] = x[r * DIN + 0];
        cy[k] = x[r * DIN + 1];
        cz[k] = x[r * DIN + 2];
    }

    float acc[RPT][8];
#pragma unroll
    for (int k = 0; k < RPT; ++k)
#pragma unroll
        for (int q = 0; q < 8; ++q) acc[k][q] = 0.0f;

    __syncthreads();

    int jbeg = jhalf * 64;
#pragma unroll 2
    for (int jj = jbeg; jj < jbeg + 64; ++jj) {
        float4 cj = sA[jj];
        float4 q0 = sB[jj];
        float4 q1 = sC[jj];
#pragma unroll
        for (int k = 0; k < RPT; ++k) {
            // exact ref order: (|dx| + |dy|) + |dz|
            float t = fabsf(cx[k] - cj.x) + fabsf(cy[k] - cj.y) + fabsf(cz[k] - cj.z);
            float w = (t <= CUTOFF) ? 1.0f : 0.0f;
            acc[k][0] = fmaf(w, cj.w, acc[k][0]);
            acc[k][1] = fmaf(w, q0.x, acc[k][1]);
            acc[k][2] = fmaf(w, q0.y, acc[k][2]);
            acc[k][3] = fmaf(w, q0.z, acc[k][3]);
            acc[k][4] = fmaf(w, q0.w, acc[k][4]);
            acc[k][5] = fmaf(w, q1.x, acc[k][5]);
            acc[k][6] = fmaf(w, q1.y, acc[k][6]);
            acc[k][7] = fmaf(w, q1.z, acc[k][7]);
        }
    }

    // cross-half reduce: half 1 dumps to LDS (stride 65 words -> 2-way banks = free)
    if (jhalf == 1) {
#pragma unroll
        for (int k = 0; k < RPT; ++k)
#pragma unroll
            for (int q = 0; q < 8; ++q) sRed[lane * RSTRIDE + k * 8 + q] = acc[k][q];
    }
    __syncthreads();
    if (jhalf == 0) {
#pragma unroll
        for (int k = 0; k < RPT; ++k) {
            int r = r0 + 128 * k;
#pragma unroll
            for (int q = 0; q < 8; ++q) {
                float v = acc[k][q] + sRed[lane * RSTRIDE + k * 8 + q];
                atomicAdd(&accum[q * NN + r], v);   // 64 consecutive words per instr
            }
        }
    }
}

// ---------------- K4: recompute row features, finalize, encoder/decoder, write out -------
__global__ __launch_bounds__(256) void k4_final(
    const float* __restrict__ x,
    const float* __restrict__ W1, const float* __restrict__ b1,
    const float* __restrict__ W2, const float* __restrict__ b2,
    const float* __restrict__ W3, const float* __restrict__ b3,
    const float* __restrict__ We, const float* __restrict__ be,
    const float* __restrict__ Wd, const float* __restrict__ bd,
    const float* __restrict__ accum, float* __restrict__ out)
{
    int n = blockIdx.x * 256 + threadIdx.x;

    float cn[3], E, ev[7];
    node_feats(x, W1, b1, W2, b2, W3, b3, n, cn, E, ev);

    // remove diagonal (dist=0 always passes cutoff); bit-identical recompute -> exact
    float denom = accum[0 * NN + n] - E;
    denom = fmaxf(denom, 1e-30f);
    float inv = 1.0f / denom;

    float inp[14];
#pragma unroll
    for (int d = 0; d < DIN; ++d) inp[d] = x[n * DIN + d];
#pragma unroll
    for (int q = 0; q < 7; ++q) inp[7 + q] = (accum[(q + 1) * NN + n] - ev[q]) * inv;

    float codes[DH];
#pragma unroll
    for (int k = 0; k < DH; ++k) {
        float t = be[k];
#pragma unroll
        for (int d = 0; d < 14; ++d) t = fmaf(We[k * 14 + d], inp[d], t);
        codes[k] = leaky(t);
    }
#pragma unroll
    for (int cc = 0; cc < DIN; ++cc) {
        float t = bd[cc];
#pragma unroll
        for (int k = 0; k < DH; ++k) t = fmaf(Wd[cc * DH + k], codes[k], t);
        out[(size_t)n * DIN + cc] = t;
    }
}

extern "C" void kernel_launch(void* const* d_in, const int* in_sizes, int n_in,
                              void* d_out, int out_size, void* d_ws, size_t ws_size,
                              hipStream_t stream) {
    const float* x  = (const float*)d_in[0];
    const float* W1 = (const float*)d_in[1];
    const float* b1 = (const float*)d_in[2];
    const float* W2 = (const float*)d_in[3];
    const float* b2 = (const float*)d_in[4];
    const float* W3 = (const float*)d_in[5];
    const float* b3 = (const float*)d_in[6];
    const float* We = (const float*)d_in[7];
    const float* be = (const float*)d_in[8];
    const float* Wd = (const float*)d_in[9];
    const float* bd = (const float*)d_in[10];
    float* out = (float*)d_out;

    float* accum = (float*)d_ws;  // 8 * 8192 * 4 = 262144 B

    hipMemsetAsync(accum, 0, 8 * NN * sizeof(float), stream);
    dim3 g3(8, NCHUNK);  // (8, 64) = 512 blocks
    k3_fused<<<g3, 256, 0, stream>>>(x, W1, b1, W2, b2, W3, b3, accum);
    k4_final<<<32, 256, 0, stream>>>(x, W1, b1, W2, b2, W3, b3, We, be, Wd, bd, accum, out);
}

// Round 7
// 113.401 us; speedup vs baseline: 1.1535x; 1.0743x over previous
//
#include <hip/hip_runtime.h>

#define NN 8192
#define DIN 7
#define DH 8
#define DOUT 23
#define CUTOFF 3.6f
#define SLOPE 0.01f

#define JC 512               // j-chunk per k3 block
#define ROWS 256             // rows per k3 block (4 waves x 4 tiles x 16)
#define PPITCH 520           // padded row pitch (shorts) for P hi/lo: 520*2B=1040B, %128B rotates banks
#define NJS (JC / 32)        // 16 K-steps of 32

typedef float  v4f __attribute__((ext_vector_type(4)));
typedef short  v8s __attribute__((ext_vector_type(8)));
typedef unsigned int v4u __attribute__((ext_vector_type(4)));

__device__ __forceinline__ float leaky(float v) { return v >= 0.0f ? v : SLOPE * v; }

// Per-node feature pipeline. Single shared implementation so k3's staged E/ev and
// k4's recomputed E/ev are bit-identical up to the bf16 split (diagonal cancel).
__device__ __forceinline__ void node_feats(
    const float* __restrict__ x,
    const float* __restrict__ W1, const float* __restrict__ b1,
    const float* __restrict__ W2, const float* __restrict__ b2,
    const float* __restrict__ W3, const float* __restrict__ b3,
    int n, float coord[3], float& E, float ev[7])
{
    float xi[DIN];
#pragma unroll
    for (int d = 0; d < DIN; ++d) xi[d] = x[n * DIN + d];
    coord[0] = xi[0]; coord[1] = xi[1]; coord[2] = xi[2];

    float h1[DH];
#pragma unroll
    for (int k = 0; k < DH; ++k) {
        float t = b1[k];
#pragma unroll
        for (int d = 0; d < DIN; ++d) t = fmaf(W1[k * DIN + d], xi[d], t);
        h1[k] = leaky(t);
    }
    float h2[DH];
#pragma unroll
    for (int k = 0; k < DH; ++k) {
        float t = b2[k];
#pragma unroll
        for (int d = 0; d < DH; ++d) t = fmaf(W2[k * DH + d], h1[d], t);
        h2[k] = leaky(t);
    }
    float h3[DOUT];
#pragma unroll
    for (int m = 0; m < DOUT; ++m) {
        float t = b3[m];
#pragma unroll
        for (int d = 0; d < DH; ++d) t = fmaf(W3[m * DH + d], h2[d], t);
        h3[m] = t;
    }
    float s = 0.0f;
#pragma unroll
    for (int k = 0; k < 8; ++k) s = fmaf(h3[7 + k], h3[15 + k], s);
    // |s| ~ O(1) (weights scaled 0.1) -> exp without max-shift is safe in fp32;
    // softmax ratio is shift-invariant so this matches the reference.
    E = expf(s);
#pragma unroll
    for (int q = 0; q < 7; ++q) ev[q] = h3[q] * E;
}

// ---------------- K3: C(8192x8) = W(0/1 mask) x P via bf16 MFMA ------------------------
// grid (32, 16): blockIdx.x -> 256-row tile, blockIdx.y -> 512-j chunk.
// Block = 4 waves; wave owns 4 row-tiles of 16; K-loop over 16 slices of 32 j.
// P split hi+lo bf16 (rel err ~2^-16), masks exact in bf16; both MFMAs chain into fp32 C.
__global__ __launch_bounds__(256, 2) void k3_mfma(
    const float* __restrict__ x,
    const float* __restrict__ W1, const float* __restrict__ b1,
    const float* __restrict__ W2, const float* __restrict__ b2,
    const float* __restrict__ W3, const float* __restrict__ b3,
    float* __restrict__ accum)
{
    __shared__ __attribute__((aligned(16))) float sCx[JC];
    __shared__ __attribute__((aligned(16))) float sCy[JC];
    __shared__ __attribute__((aligned(16))) float sCz[JC];
    __shared__ __attribute__((aligned(16))) short sPhi[8 * PPITCH];
    __shared__ __attribute__((aligned(16))) short sPlo[8 * PPITCH];

    int tid = threadIdx.x;
    int jBase = blockIdx.y * JC;
    int rowBase = blockIdx.x * ROWS;

    // stage: 2 j's per thread -> coords f32, P as bf16 hi/lo in [q][j] layout
#pragma unroll
    for (int rep = 0; rep < 2; ++rep) {
        int lj = rep * 256 + tid;
        int j = jBase + lj;
        float cj[3], E, ev[7];
        node_feats(x, W1, b1, W2, b2, W3, b3, j, cj, E, ev);
        sCx[lj] = cj[0]; sCy[lj] = cj[1]; sCz[lj] = cj[2];
        float pv[8] = {ev[0], ev[1], ev[2], ev[3], ev[4], ev[5], ev[6], E};
#pragma unroll
        for (int q = 0; q < 8; ++q) {
            float v = pv[q];
            unsigned u = __float_as_uint(v);
            float resid = v - __uint_as_float(u & 0xFFFF0000u);   // exact
            sPhi[q * PPITCH + lj] = (short)(u >> 16);
            sPlo[q * PPITCH + lj] = (short)(__float_as_uint(resid) >> 16);
        }
    }

    int wave = tid >> 6;
    int lane = tid & 63;
    int lm = lane & 15;      // A-row within tile / C-col (q)
    int q4 = lane >> 4;      // k-slice quad
    int bcol = lm & 7;       // B-row in [q][j] store; cols 8-15 mirror 0-7 (never stored)

    // row coords for this lane's 4 tiles (row = lane&15 within each 16-row tile)
    float rxt[4], ryt[4], rzt[4];
#pragma unroll
    for (int t = 0; t < 4; ++t) {
        int r = rowBase + wave * 64 + t * 16 + lm;
        rxt[t] = x[r * DIN + 0];
        ryt[t] = x[r * DIN + 1];
        rzt[t] = x[r * DIN + 2];
    }

    v4f c0 = {0.f, 0.f, 0.f, 0.f};
    v4f c1 = {0.f, 0.f, 0.f, 0.f};
    v4f c2 = {0.f, 0.f, 0.f, 0.f};
    v4f c3 = {0.f, 0.f, 0.f, 0.f};

    __syncthreads();

#pragma unroll 2
    for (int js = 0; js < NJS; ++js) {
        int jb = js * 32 + q4 * 8;      // this lane's 8 consecutive j within the slice
        float4 x0 = *(const float4*)&sCx[jb];
        float4 x1 = *(const float4*)&sCx[jb + 4];
        float4 y0 = *(const float4*)&sCy[jb];
        float4 y1 = *(const float4*)&sCy[jb + 4];
        float4 z0 = *(const float4*)&sCz[jb];
        float4 z1 = *(const float4*)&sCz[jb + 4];
        v8s bhi = *(const v8s*)&sPhi[bcol * PPITCH + jb];
        v8s blo = *(const v8s*)&sPlo[bcol * PPITCH + jb];
        float jx[8] = {x0.x, x0.y, x0.z, x0.w, x1.x, x1.y, x1.z, x1.w};
        float jy[8] = {y0.x, y0.y, y0.z, y0.w, y1.x, y1.y, y1.z, y1.w};
        float jz[8] = {z0.x, z0.y, z0.z, z0.w, z1.x, z1.y, z1.z, z1.w};

#pragma unroll
        for (int t = 0; t < 4; ++t) {
            v4u pk;
#pragma unroll
            for (int i2 = 0; i2 < 4; ++i2) {
                // exact ref order: (|dx| + |dy|) + |dz|
                float ta = fabsf(rxt[t] - jx[2 * i2]) + fabsf(ryt[t] - jy[2 * i2])
                         + fabsf(rzt[t] - jz[2 * i2]);
                float tb = fabsf(rxt[t] - jx[2 * i2 + 1]) + fabsf(ryt[t] - jy[2 * i2 + 1])
                         + fabsf(rzt[t] - jz[2 * i2 + 1]);
                unsigned wa = (ta <= CUTOFF) ? 0x3F80u : 0u;   // bf16 1.0
                unsigned wb = (tb <= CUTOFF) ? 0x3F80u : 0u;
                pk[i2] = wa | (wb << 16);
            }
            v8s a = __builtin_bit_cast(v8s, pk);
            v4f* cp = (t == 0) ? &c0 : (t == 1) ? &c1 : (t == 2) ? &c2 : &c3;
            *cp = __builtin_amdgcn_mfma_f32_16x16x32_bf16(a, bhi, *cp, 0, 0, 0);
            *cp = __builtin_amdgcn_mfma_f32_16x16x32_bf16(a, blo, *cp, 0, 0, 0);
        }
    }

    // C layout: col=lane&15 (q), row=(lane>>4)*4+reg. Only cols 0..7 are real.
    if (lm < 8) {
        v4f cc[4] = {c0, c1, c2, c3};
#pragma unroll
        for (int t = 0; t < 4; ++t) {
            int rb = rowBase + wave * 64 + t * 16 + q4 * 4;
#pragma unroll
            for (int reg = 0; reg < 4; ++reg)
                atomicAdd(&accum[lm * NN + rb + reg], cc[t][reg]);
        }
    }
}

// ---------------- K4: recompute row features, finalize, encoder/decoder, write out ------
__global__ __launch_bounds__(256) void k4_final(
    const float* __restrict__ x,
    const float* __restrict__ W1, const float* __restrict__ b1,
    const float* __restrict__ W2, const float* __restrict__ b2,
    const float* __restrict__ W3, const float* __restrict__ b3,
    const float* __restrict__ We, const float* __restrict__ be,
    const float* __restrict__ Wd, const float* __restrict__ bd,
    const float* __restrict__ accum, float* __restrict__ out)
{
    int n = blockIdx.x * 256 + threadIdx.x;

    float cn[3], E, ev[7];
    node_feats(x, W1, b1, W2, b2, W3, b3, n, cn, E, ev);

    // accum cols: q=0..6 -> sum w*ev[q]; q=7 -> sum w*E (denominator incl. diagonal)
    float denom = accum[7 * NN + n] - E;
    denom = fmaxf(denom, 1e-30f);
    float inv = 1.0f / denom;

    float inp[14];
#pragma unroll
    for (int d = 0; d < DIN; ++d) inp[d] = x[n * DIN + d];
#pragma unroll
    for (int q = 0; q < 7; ++q) inp[7 + q] = (accum[q * NN + n] - ev[q]) * inv;

    float codes[DH];
#pragma unroll
    for (int k = 0; k < DH; ++k) {
        float t = be[k];
#pragma unroll
        for (int d = 0; d < 14; ++d) t = fmaf(We[k * 14 + d], inp[d], t);
        codes[k] = leaky(t);
    }
#pragma unroll
    for (int cc = 0; cc < DIN; ++cc) {
        float t = bd[cc];
#pragma unroll
        for (int k = 0; k < DH; ++k) t = fmaf(Wd[cc * DH + k], codes[k], t);
        out[(size_t)n * DIN + cc] = t;
    }
}

extern "C" void kernel_launch(void* const* d_in, const int* in_sizes, int n_in,
                              void* d_out, int out_size, void* d_ws, size_t ws_size,
                              hipStream_t stream) {
    const float* x  = (const float*)d_in[0];
    const float* W1 = (const float*)d_in[1];
    const float* b1 = (const float*)d_in[2];
    const float* W2 = (const float*)d_in[3];
    const float* b2 = (const float*)d_in[4];
    const float* W3 = (const float*)d_in[5];
    const float* b3 = (const float*)d_in[6];
    const float* We = (const float*)d_in[7];
    const float* be = (const float*)d_in[8];
    const float* Wd = (const float*)d_in[9];
    const float* bd = (const float*)d_in[10];
    float* out = (float*)d_out;

    float* accum = (float*)d_ws;  // 8 * 8192 * 4 = 262144 B

    hipMemsetAsync(accum, 0, 8 * NN * sizeof(float), stream);
    dim3 g3(NN / ROWS, NN / JC);  // (32, 16) = 512 blocks
    k3_mfma<<<g3, 256, 0, stream>>>(x, W1, b1, W2, b2, W3, b3, accum);
    k4_final<<<32, 256, 0, stream>>>(x, W1, b1, W2, b2, W3, b3, We, be, Wd, bd, accum, out);
}